// Round 1
// baseline (242.095 us; speedup 1.0000x reference)
//
#include <hip/hip_runtime.h>
#include <math.h>

#define SEQ   8
#define DFF   32
#define NL    2
#define VOCAB 256
#define BATCH 131072

__global__ __launch_bounds__(256) void seqtx_kernel(
    const int*   __restrict__ x,
    const float* __restrict__ Wqkv, const float* __restrict__ bqkv,
    const float* __restrict__ Wo,   const float* __restrict__ bo,
    const float* __restrict__ W1,   const float* __restrict__ b1,
    const float* __restrict__ W2,   const float* __restrict__ b2,
    const float* __restrict__ g1,   const float* __restrict__ be1,
    const float* __restrict__ g2,   const float* __restrict__ be2,
    const float* __restrict__ Wout, const float* __restrict__ bout,
    float* __restrict__ out)
{
    __shared__ float hfin0[256];
    __shared__ float hfin1[256];

    const int tid   = threadIdx.x;
    const int bbase = blockIdx.x * 256;
    const int b     = bbase + tid;

    // ---------------- phase 1: per-thread micro-transformer ----------------
    float h0[SEQ], h1[SEQ];
    {
        const int4* xp = reinterpret_cast<const int4*>(x + (size_t)b * SEQ);
        int4 xa = xp[0];
        int4 xb = xp[1];
        const float inv255 = 1.0f / 255.0f;
        const float inv7   = 1.0f / 7.0f;
        h0[0] = (float)xa.x * inv255;  h0[1] = (float)xa.y * inv255;
        h0[2] = (float)xa.z * inv255;  h0[3] = (float)xa.w * inv255;
        h0[4] = (float)xb.x * inv255;  h0[5] = (float)xb.y * inv255;
        h0[6] = (float)xb.z * inv255;  h0[7] = (float)xb.w * inv255;
        #pragma unroll
        for (int s = 0; s < SEQ; ++s) h1[s] = (float)s * inv7;
    }

    #pragma unroll
    for (int l = 0; l < NL; ++l) {
        // ---- QKV projection (Wqkv[l] is (6,2) row-major) ----
        const float* wq = Wqkv + l * 12;
        const float* bq = bqkv + l * 6;
        float w00 = wq[0],  w01 = wq[1],  w10 = wq[2],  w11 = wq[3];
        float w20 = wq[4],  w21 = wq[5],  w30 = wq[6],  w31 = wq[7];
        float w40 = wq[8],  w41 = wq[9],  w50 = wq[10], w51 = wq[11];
        float bq0 = bq[0], bq1 = bq[1], bq2 = bq[2], bq3 = bq[3], bq4 = bq[4], bq5 = bq[5];

        float q[2][SEQ], k[2][SEQ], v[2][SEQ];
        #pragma unroll
        for (int s = 0; s < SEQ; ++s) {
            float a = h0[s], c = h1[s];
            q[0][s] = w00 * a + w01 * c + bq0;
            q[1][s] = w10 * a + w11 * c + bq1;
            k[0][s] = w20 * a + w21 * c + bq2;
            k[1][s] = w30 * a + w31 * c + bq3;
            v[0][s] = w40 * a + w41 * c + bq4;
            v[1][s] = w50 * a + w51 * c + bq5;
        }

        // ---- attention per head (hd=1 -> scale = 1) ----
        float o[2][SEQ];
        #pragma unroll
        for (int hh = 0; hh < 2; ++hh) {
            #pragma unroll
            for (int qi = 0; qi < SEQ; ++qi) {
                float sc[SEQ];
                float m = -1e30f;
                #pragma unroll
                for (int ki = 0; ki < SEQ; ++ki) {
                    sc[ki] = q[hh][qi] * k[hh][ki];
                    m = fmaxf(m, sc[ki]);
                }
                float sum = 0.0f, acc = 0.0f;
                #pragma unroll
                for (int ki = 0; ki < SEQ; ++ki) {
                    float e = __expf(sc[ki] - m);
                    sum += e;
                    acc += e * v[hh][ki];
                }
                o[hh][qi] = acc / sum;
            }
        }

        // ---- output proj + residual + LN1 ----
        const float* wo = Wo + l * 4;
        float wo00 = wo[0], wo01 = wo[1], wo10 = wo[2], wo11 = wo[3];
        float bo0 = bo[l * 2 + 0], bo1 = bo[l * 2 + 1];
        float ga0 = g1[l * 2 + 0], ga1 = g1[l * 2 + 1];
        float ba0 = be1[l * 2 + 0], ba1 = be1[l * 2 + 1];
        #pragma unroll
        for (int s = 0; s < SEQ; ++s) {
            float p0 = wo00 * o[0][s] + wo01 * o[1][s] + bo0;
            float p1 = wo10 * o[0][s] + wo11 * o[1][s] + bo1;
            float a = h0[s] + p0, c = h1[s] + p1;
            float d = 0.5f * (a - c);               // a - mu ; c - mu = -d
            float rstd = rsqrtf(d * d + 1e-5f);     // var = d^2
            float nd = d * rstd;
            h0[s] =  nd * ga0 + ba0;
            h1[s] = -nd * ga1 + ba1;
        }

        // ---- FF: W1 (32,2), exact GELU, W2 (2,32) ----
        float f0[SEQ], f1[SEQ];
        float b20 = b2[l * 2 + 0], b21 = b2[l * 2 + 1];
        #pragma unroll
        for (int s = 0; s < SEQ; ++s) { f0[s] = b20; f1[s] = b21; }
        #pragma unroll
        for (int j = 0; j < DFF; ++j) {
            float w1a = W1[l * 64 + j * 2 + 0];
            float w1b = W1[l * 64 + j * 2 + 1];
            float bb  = b1[l * 32 + j];
            float w2a = W2[l * 64 + j];          // W2[l][0][j]
            float w2b = W2[l * 64 + 32 + j];     // W2[l][1][j]
            #pragma unroll
            for (int s = 0; s < SEQ; ++s) {
                float t = w1a * h0[s] + w1b * h1[s] + bb;
                float g = 0.5f * t * (1.0f + erff(t * 0.70710678118654752f));
                f0[s] += g * w2a;
                f1[s] += g * w2b;
            }
        }

        // ---- residual + LN2 ----
        float gb0 = g2[l * 2 + 0], gb1 = g2[l * 2 + 1];
        float bb0 = be2[l * 2 + 0], bb1 = be2[l * 2 + 1];
        #pragma unroll
        for (int s = 0; s < SEQ; ++s) {
            float a = h0[s] + f0[s], c = h1[s] + f1[s];
            float d = 0.5f * (a - c);
            float rstd = rsqrtf(d * d + 1e-5f);
            float nd = d * rstd;
            h0[s] =  nd * gb0 + bb0;
            h1[s] = -nd * gb1 + bb1;
        }
    }

    hfin0[tid] = h0[SEQ - 1];
    hfin1[tid] = h1[SEQ - 1];
    __syncthreads();

    // ---------------- phase 2: vocab projection, coalesced float4 stores ----
    // thread t handles row r = t>>6 (uniform per wave) and vocab [cg, cg+4)
    const int r  = tid >> 6;
    const int cg = (tid & 63) * 4;

    float wv0x = Wout[(cg + 0) * 2 + 0], wv0y = Wout[(cg + 0) * 2 + 1];
    float wv1x = Wout[(cg + 1) * 2 + 0], wv1y = Wout[(cg + 1) * 2 + 1];
    float wv2x = Wout[(cg + 2) * 2 + 0], wv2y = Wout[(cg + 2) * 2 + 1];
    float wv3x = Wout[(cg + 3) * 2 + 0], wv3y = Wout[(cg + 3) * 2 + 1];
    float bv0 = bout[cg + 0], bv1 = bout[cg + 1], bv2 = bout[cg + 2], bv3 = bout[cg + 3];

    for (int bb = 0; bb < 256; bb += 4) {
        int row = bb + r;                     // wave-uniform
        float a = hfin0[row];                 // LDS broadcast
        float c = hfin1[row];
        float4 res;
        res.x = wv0x * a + wv0y * c + bv0;
        res.y = wv1x * a + wv1y * c + bv1;
        res.z = wv2x * a + wv2y * c + bv2;
        res.w = wv3x * a + wv3y * c + bv3;
        *reinterpret_cast<float4*>(&out[(size_t)(bbase + row) * VOCAB + cg]) = res;
    }
}

extern "C" void kernel_launch(void* const* d_in, const int* in_sizes, int n_in,
                              void* d_out, int out_size, void* d_ws, size_t ws_size,
                              hipStream_t stream) {
    const int*   x    = (const int*)  d_in[0];
    const float* Wqkv = (const float*)d_in[1];
    const float* bqkv = (const float*)d_in[2];
    const float* Wo   = (const float*)d_in[3];
    const float* bo   = (const float*)d_in[4];
    const float* W1   = (const float*)d_in[5];
    const float* b1   = (const float*)d_in[6];
    const float* W2   = (const float*)d_in[7];
    const float* b2   = (const float*)d_in[8];
    const float* g1   = (const float*)d_in[9];
    const float* be1  = (const float*)d_in[10];
    const float* g2   = (const float*)d_in[11];
    const float* be2  = (const float*)d_in[12];
    const float* Wout = (const float*)d_in[13];
    const float* bout = (const float*)d_in[14];
    float* out = (float*)d_out;

    seqtx_kernel<<<BATCH / 256, 256, 0, stream>>>(
        x, Wqkv, bqkv, Wo, bo, W1, b1, W2, b2, g1, be1, g2, be2, Wout, bout, out);
}

// Round 2
// 45.703 us; speedup vs baseline: 5.2971x; 5.2971x over previous
//
#include <hip/hip_runtime.h>
#include <math.h>

#define SEQ   8
#define DFF   32
#define NL    2
#define VOCAB 256
#define BATCH 131072

// 8 lanes per batch element (lane = sequence position). 256 threads/block
// = 32 elements/block. Attention exchanges k,v across the 8-lane group via
// __shfl(width=8) — same wave, lockstep, no barrier needed.
__global__ __launch_bounds__(256, 4) void seqtx_fused(
    const int*   __restrict__ x,
    const float* __restrict__ Wqkv, const float* __restrict__ bqkv,
    const float* __restrict__ Wo,   const float* __restrict__ bo,
    const float* __restrict__ W1,   const float* __restrict__ b1,
    const float* __restrict__ W2,   const float* __restrict__ b2,
    const float* __restrict__ g1,   const float* __restrict__ be1,
    const float* __restrict__ g2,   const float* __restrict__ be2,
    const float* __restrict__ Wout, const float* __restrict__ bout,
    float* __restrict__ out)
{
    __shared__ float hf0[32];
    __shared__ float hf1[32];

    const int tid = threadIdx.x;
    const int sub = tid & 7;                       // position within element
    const int gid = blockIdx.x * 256 + tid;        // global lane id
    // element index = gid >> 3 ; x[elem*8 + sub] == x[gid] (coalesced)

    float h0 = (float)x[gid] * (1.0f / 255.0f);
    float h1 = (float)sub * (1.0f / 7.0f);

    #pragma unroll
    for (int l = 0; l < NL; ++l) {
        // ---- QKV projection: Wqkv[l] is (6,2) row-major; all loads uniform ----
        const float* wq = Wqkv + l * 12;
        const float* bq = bqkv + l * 6;
        float q0 = fmaf(wq[0],  h0, fmaf(wq[1],  h1, bq[0]));
        float q1 = fmaf(wq[2],  h0, fmaf(wq[3],  h1, bq[1]));
        float k0 = fmaf(wq[4],  h0, fmaf(wq[5],  h1, bq[2]));
        float k1 = fmaf(wq[6],  h0, fmaf(wq[7],  h1, bq[3]));
        float v0 = fmaf(wq[8],  h0, fmaf(wq[9],  h1, bq[4]));
        float v1 = fmaf(wq[10], h0, fmaf(wq[11], h1, bq[5]));

        // ---- attention (hd=1, scale=1): this lane computes its own row ----
        float o0, o1;
        {
            float sc[SEQ];
            float m = -1e30f;
            #pragma unroll
            for (int j = 0; j < SEQ; ++j) {
                sc[j] = q0 * __shfl(k0, j, SEQ);
                m = fmaxf(m, sc[j]);
            }
            float sum = 0.0f, acc = 0.0f;
            #pragma unroll
            for (int j = 0; j < SEQ; ++j) {
                float e = __expf(sc[j] - m);
                sum += e;
                acc = fmaf(e, __shfl(v0, j, SEQ), acc);
            }
            o0 = acc / sum;
        }
        {
            float sc[SEQ];
            float m = -1e30f;
            #pragma unroll
            for (int j = 0; j < SEQ; ++j) {
                sc[j] = q1 * __shfl(k1, j, SEQ);
                m = fmaxf(m, sc[j]);
            }
            float sum = 0.0f, acc = 0.0f;
            #pragma unroll
            for (int j = 0; j < SEQ; ++j) {
                float e = __expf(sc[j] - m);
                sum += e;
                acc = fmaf(e, __shfl(v1, j, SEQ), acc);
            }
            o1 = acc / sum;
        }

        // ---- output proj + residual + LN1 (D=2 closed form) ----
        const float* wo = Wo + l * 4;
        float p0 = fmaf(wo[0], o0, fmaf(wo[1], o1, bo[l * 2 + 0]));
        float p1 = fmaf(wo[2], o0, fmaf(wo[3], o1, bo[l * 2 + 1]));
        float a = h0 + p0, c = h1 + p1;
        float d = 0.5f * (a - c);                    // a-mu; c-mu = -d
        float nd = d * rsqrtf(fmaf(d, d, 1e-5f));    // var = d^2
        h0 = fmaf( nd, g1[l * 2 + 0], be1[l * 2 + 0]);
        h1 = fmaf(-nd, g1[l * 2 + 1], be1[l * 2 + 1]);

        // ---- FF: W1 (32,2), exact GELU, W2 (2,32); weights uniform ----
        float f0 = b2[l * 2 + 0];
        float f1 = b2[l * 2 + 1];
        const float* w1p = W1 + l * 64;
        const float* b1p = b1 + l * 32;
        const float* w2p = W2 + l * 64;
        for (int j = 0; j < DFF; ++j) {
            float t = fmaf(w1p[j * 2], h0, fmaf(w1p[j * 2 + 1], h1, b1p[j]));
            float g = 0.5f * t * (1.0f + erff(t * 0.70710678118654752f));
            f0 = fmaf(g, w2p[j], f0);
            f1 = fmaf(g, w2p[32 + j], f1);
        }

        // ---- residual + LN2 ----
        a = h0 + f0; c = h1 + f1;
        d = 0.5f * (a - c);
        nd = d * rsqrtf(fmaf(d, d, 1e-5f));
        h0 = fmaf( nd, g2[l * 2 + 0], be2[l * 2 + 0]);
        h1 = fmaf(-nd, g2[l * 2 + 1], be2[l * 2 + 1]);
    }

    // ---- stage final-position hidden state (2 floats per element) ----
    if (sub == SEQ - 1) {
        hf0[tid >> 3] = h0;
        hf1[tid >> 3] = h1;
    }
    __syncthreads();

    // ---- vocab projection, coalesced float4 stores ----
    // wave w handles row (it*4 + w); lane handles vocab quad cg..cg+3
    const int r  = tid >> 6;                 // wave id (row offset), uniform/wave
    const int cg = (tid & 63) * 4;

    const float2* wvp = reinterpret_cast<const float2*>(Wout);
    float2 wv0 = wvp[cg + 0];
    float2 wv1 = wvp[cg + 1];
    float2 wv2 = wvp[cg + 2];
    float2 wv3 = wvp[cg + 3];
    float4 bv  = *reinterpret_cast<const float4*>(bout + cg);

    const size_t rowbase = (size_t)blockIdx.x * 32;
    #pragma unroll
    for (int it = 0; it < 8; ++it) {
        int row = it * 4 + r;                // wave-uniform
        float aa = hf0[row];                 // LDS broadcast
        float cc = hf1[row];
        float4 res;
        res.x = fmaf(wv0.x, aa, fmaf(wv0.y, cc, bv.x));
        res.y = fmaf(wv1.x, aa, fmaf(wv1.y, cc, bv.y));
        res.z = fmaf(wv2.x, aa, fmaf(wv2.y, cc, bv.z));
        res.w = fmaf(wv3.x, aa, fmaf(wv3.y, cc, bv.w));
        *reinterpret_cast<float4*>(&out[(rowbase + row) * VOCAB + cg]) = res;
    }
}

extern "C" void kernel_launch(void* const* d_in, const int* in_sizes, int n_in,
                              void* d_out, int out_size, void* d_ws, size_t ws_size,
                              hipStream_t stream) {
    const int*   x    = (const int*)  d_in[0];
    const float* Wqkv = (const float*)d_in[1];
    const float* bqkv = (const float*)d_in[2];
    const float* Wo   = (const float*)d_in[3];
    const float* bo   = (const float*)d_in[4];
    const float* W1   = (const float*)d_in[5];
    const float* b1   = (const float*)d_in[6];
    const float* W2   = (const float*)d_in[7];
    const float* b2   = (const float*)d_in[8];
    const float* g1   = (const float*)d_in[9];
    const float* be1  = (const float*)d_in[10];
    const float* g2   = (const float*)d_in[11];
    const float* be2  = (const float*)d_in[12];
    const float* Wout = (const float*)d_in[13];
    const float* bout = (const float*)d_in[14];
    float* out = (float*)d_out;

    // 32 elements per block -> BATCH/32 = 4096 blocks
    seqtx_fused<<<BATCH / 32, 256, 0, stream>>>(
        x, Wqkv, bqkv, Wo, bo, W1, b1, W2, b2, g1, be1, g2, be2, Wout, bout, out);
}

// Round 3
// 40.897 us; speedup vs baseline: 5.9196x; 1.1175x over previous
//
#include <hip/hip_runtime.h>
#include <math.h>

#define SEQ   8
#define DFF   32
#define NL    2
#define VOCAB 256
#define BATCH 131072
#define TBL_N 4096   // intervals; entry i packs f(nd_i), f(nd_{i+1})

// FF(h(nd)) for layer l: h0 = nd*g1+be1 (h1 = -nd*g1'+be1'), exact-erf GELU MLP.
__device__ __forceinline__ void ff_eval(
    const float* __restrict__ W1, const float* __restrict__ b1,
    const float* __restrict__ W2, const float* __restrict__ b2,
    const float* __restrict__ g1, const float* __restrict__ be1,
    int l, float nd, float& f0, float& f1)
{
    float h0 = fmaf( nd, g1[l*2+0], be1[l*2+0]);
    float h1 = fmaf(-nd, g1[l*2+1], be1[l*2+1]);
    f0 = b2[l*2+0];
    f1 = b2[l*2+1];
    const float* w1p = W1 + l*64;
    const float* b1p = b1 + l*32;
    const float* w2p = W2 + l*64;
    for (int j = 0; j < DFF; ++j) {
        float t = fmaf(w1p[j*2], h0, fmaf(w1p[j*2+1], h1, b1p[j]));
        float g = 0.5f * t * (1.0f + erff(t * 0.70710678118654752f));
        f0 = fmaf(g, w2p[j], f0);
        f1 = fmaf(g, w2p[32+j], f1);
    }
}

__global__ __launch_bounds__(256) void build_tables(
    const float* __restrict__ W1, const float* __restrict__ b1,
    const float* __restrict__ W2, const float* __restrict__ b2,
    const float* __restrict__ g1, const float* __restrict__ be1,
    float4* __restrict__ T4)
{
    int idx = blockIdx.x * 256 + threadIdx.x;
    if (idx >= NL * TBL_N) return;
    int l = idx >> 12;            // / TBL_N
    int i = idx & (TBL_N - 1);
    float nd0 = -1.0f + (float)i       * (2.0f / TBL_N);
    float nd1 = -1.0f + (float)(i + 1) * (2.0f / TBL_N);
    float a0, a1, c0, c1;
    ff_eval(W1, b1, W2, b2, g1, be1, l, nd0, a0, a1);
    ff_eval(W1, b1, W2, b2, g1, be1, l, nd1, c0, c1);
    T4[idx] = make_float4(a0, a1, c0, c1);
}

// 8 lanes per batch element (lane = position); k/v exchanged via __shfl width 8.
// FF replaced by table lookup in nd; final vocab row = nd_final*u + w.
__global__ __launch_bounds__(256, 4) void seqtx_main(
    const int*   __restrict__ x,
    const float* __restrict__ Wqkv, const float* __restrict__ bqkv,
    const float* __restrict__ Wo,   const float* __restrict__ bo,
    const float* __restrict__ g1,   const float* __restrict__ be1,
    const float* __restrict__ g2,   const float* __restrict__ be2,
    const float* __restrict__ Wout, const float* __restrict__ bout,
    const float4* __restrict__ T4,
    float* __restrict__ out)
{
    __shared__ float snd[32];

    const int tid = threadIdx.x;
    const int sub = tid & 7;
    const int gid = blockIdx.x * 256 + tid;

    float h0 = (float)x[gid] * (1.0f / 255.0f);
    float h1 = (float)sub * (1.0f / 7.0f);
    float ndl = 0.0f;

    #pragma unroll
    for (int l = 0; l < NL; ++l) {
        // ---- QKV projection (uniform scalar weights) ----
        const float* wq = Wqkv + l * 12;
        const float* bq = bqkv + l * 6;
        float q0 = fmaf(wq[0],  h0, fmaf(wq[1],  h1, bq[0]));
        float q1 = fmaf(wq[2],  h0, fmaf(wq[3],  h1, bq[1]));
        float k0 = fmaf(wq[4],  h0, fmaf(wq[5],  h1, bq[2]));
        float k1 = fmaf(wq[6],  h0, fmaf(wq[7],  h1, bq[3]));
        float v0 = fmaf(wq[8],  h0, fmaf(wq[9],  h1, bq[4]));
        float v1 = fmaf(wq[10], h0, fmaf(wq[11], h1, bq[5]));

        // ---- attention, hd=1, scale=1; softmax without max-sub (|s|<~1) ----
        float q0e = q0 * 1.44269504f;    // fold log2(e) into q
        float q1e = q1 * 1.44269504f;
        float s0 = 0.0f, a0 = 0.0f, s1 = 0.0f, a1 = 0.0f;
        #pragma unroll
        for (int j = 0; j < SEQ; ++j) {
            float kj0 = __shfl(k0, j, SEQ);
            float vj0 = __shfl(v0, j, SEQ);
            float e0  = __builtin_amdgcn_exp2f(q0e * kj0);
            s0 += e0;  a0 = fmaf(e0, vj0, a0);
            float kj1 = __shfl(k1, j, SEQ);
            float vj1 = __shfl(v1, j, SEQ);
            float e1  = __builtin_amdgcn_exp2f(q1e * kj1);
            s1 += e1;  a1 = fmaf(e1, vj1, a1);
        }
        float o0 = a0 * __builtin_amdgcn_rcpf(s0);
        float o1 = a1 * __builtin_amdgcn_rcpf(s1);

        // ---- output proj + residual + LN1 (closed form, D=2) ----
        const float* wo = Wo + l * 4;
        float p0 = fmaf(wo[0], o0, fmaf(wo[1], o1, bo[l * 2 + 0]));
        float p1 = fmaf(wo[2], o0, fmaf(wo[3], o1, bo[l * 2 + 1]));
        float a = h0 + p0, c = h1 + p1;
        float d = 0.5f * (a - c);
        float nd = d * __builtin_amdgcn_rsqf(fmaf(d, d, 1e-5f));
        h0 = fmaf( nd, g1[l * 2 + 0], be1[l * 2 + 0]);
        h1 = fmaf(-nd, g1[l * 2 + 1], be1[l * 2 + 1]);

        // ---- FF via table lookup + lerp ----
        float tf = fmaf(nd, (float)(TBL_N / 2), (float)(TBL_N / 2)); // (nd+1)*N/2
        int   i  = (int)tf;
        i = (i < 0) ? 0 : ((i > TBL_N - 1) ? TBL_N - 1 : i);
        float fr = tf - (float)i;
        float4 e4 = T4[l * TBL_N + i];       // (f0_i, f1_i, f0_i1, f1_i1), 16B aligned
        float f0 = fmaf(fr, e4.z - e4.x, e4.x);
        float f1 = fmaf(fr, e4.w - e4.y, e4.y);

        // ---- residual + LN2 (exact) ----
        a = h0 + f0;  c = h1 + f1;
        d = 0.5f * (a - c);
        float nd2 = d * __builtin_amdgcn_rsqf(fmaf(d, d, 1e-5f));
        h0 = fmaf( nd2, g2[l * 2 + 0], be2[l * 2 + 0]);
        h1 = fmaf(-nd2, g2[l * 2 + 1], be2[l * 2 + 1]);
        ndl = nd2;
    }

    if (sub == SEQ - 1) snd[tid >> 3] = ndl;
    __syncthreads();

    // ---- vocab projection: out[row][v] = nd_final*u[v] + w[v], float4 stores ----
    const int r  = tid >> 6;              // wave id -> row offset (uniform/wave)
    const int cg = (tid & 63) * 4;

    const float2* wvp = reinterpret_cast<const float2*>(Wout);
    float2 wv0 = wvp[cg + 0];
    float2 wv1 = wvp[cg + 1];
    float2 wv2 = wvp[cg + 2];
    float2 wv3 = wvp[cg + 3];
    float4 bv  = *reinterpret_cast<const float4*>(bout + cg);
    float gf0 = g2[2], gf1 = g2[3], bf0 = be2[2], bf1 = be2[3];

    float u0 = wv0.x * gf0 - wv0.y * gf1,  w0 = fmaf(wv0.x, bf0, fmaf(wv0.y, bf1, bv.x));
    float u1 = wv1.x * gf0 - wv1.y * gf1,  w1 = fmaf(wv1.x, bf0, fmaf(wv1.y, bf1, bv.y));
    float u2 = wv2.x * gf0 - wv2.y * gf1,  w2 = fmaf(wv2.x, bf0, fmaf(wv2.y, bf1, bv.z));
    float u3 = wv3.x * gf0 - wv3.y * gf1,  w3 = fmaf(wv3.x, bf0, fmaf(wv3.y, bf1, bv.w));

    const size_t rowbase = (size_t)blockIdx.x * 32;
    #pragma unroll
    for (int it = 0; it < 8; ++it) {
        int row = it * 4 + r;
        float ndv = snd[row];             // LDS broadcast (wave-uniform row)
        float4 res;
        res.x = fmaf(ndv, u0, w0);
        res.y = fmaf(ndv, u1, w1);
        res.z = fmaf(ndv, u2, w2);
        res.w = fmaf(ndv, u3, w3);
        *reinterpret_cast<float4*>(&out[(rowbase + row) * VOCAB + cg]) = res;
    }
}

extern "C" void kernel_launch(void* const* d_in, const int* in_sizes, int n_in,
                              void* d_out, int out_size, void* d_ws, size_t ws_size,
                              hipStream_t stream) {
    const int*   x    = (const int*)  d_in[0];
    const float* Wqkv = (const float*)d_in[1];
    const float* bqkv = (const float*)d_in[2];
    const float* Wo   = (const float*)d_in[3];
    const float* bo   = (const float*)d_in[4];
    const float* W1   = (const float*)d_in[5];
    const float* b1   = (const float*)d_in[6];
    const float* W2   = (const float*)d_in[7];
    const float* b2   = (const float*)d_in[8];
    const float* g1   = (const float*)d_in[9];
    const float* be1  = (const float*)d_in[10];
    const float* g2   = (const float*)d_in[11];
    const float* be2  = (const float*)d_in[12];
    const float* Wout = (const float*)d_in[13];
    const float* bout = (const float*)d_in[14];
    float* out = (float*)d_out;

    float4* T4 = (float4*)d_ws;   // 2*4096*16B = 128 KiB

    build_tables<<<(NL * TBL_N + 255) / 256, 256, 0, stream>>>(
        W1, b1, W2, b2, g1, be1, T4);

    seqtx_main<<<BATCH / 32, 256, 0, stream>>>(
        x, Wqkv, bqkv, Wo, bo, g1, be1, g2, be2, Wout, bout, T4, out);
}

// Round 4
// 33.948 us; speedup vs baseline: 7.1314x; 1.2047x over previous
//
#include <hip/hip_runtime.h>
#include <math.h>

#define SEQ   8
#define DFF   32
#define NL    2
#define VOCAB 256
#define BATCH 131072
#define TBL_N 4096   // intervals; entry i packs f(nd_i), f(nd_{i+1})

// Parallel table builder: one 32-lane half-wave per entry; lane j computes the
// j-th GELU term at both interval endpoints, butterfly-reduce, lane 0 writes.
__global__ __launch_bounds__(256) void build_tables_par(
    const float* __restrict__ W1, const float* __restrict__ b1,
    const float* __restrict__ W2, const float* __restrict__ b2,
    const float* __restrict__ g1, const float* __restrict__ be1,
    const float* __restrict__ b2b,
    float4* __restrict__ T4)
{
    int gt    = blockIdx.x * 256 + threadIdx.x;
    int entry = gt >> 5;
    int j     = gt & 31;
    if (entry >= NL * TBL_N) return;
    int l = entry >> 12;            // / TBL_N
    int i = entry & (TBL_N - 1);

    float nd0 = -1.0f + (float)i * (2.0f / TBL_N);
    float nd1 = nd0 + (2.0f / TBL_N);

    float ga = g1[l*2+0], gb = g1[l*2+1], ba = be1[l*2+0], bb = be1[l*2+1];
    float w1a = W1[l*64 + j*2], w1b = W1[l*64 + j*2 + 1], b1j = b1[l*32 + j];
    float w2a = W2[l*64 + j],   w2b = W2[l*64 + 32 + j];

    // endpoint 0
    float h0 = fmaf( nd0, ga, ba), h1 = fmaf(-nd0, gb, bb);
    float t  = fmaf(w1a, h0, fmaf(w1b, h1, b1j));
    float g  = 0.5f * t * (1.0f + erff(t * 0.70710678118654752f));
    float f00 = g * w2a, f10 = g * w2b;
    // endpoint 1
    h0 = fmaf( nd1, ga, ba); h1 = fmaf(-nd1, gb, bb);
    t  = fmaf(w1a, h0, fmaf(w1b, h1, b1j));
    g  = 0.5f * t * (1.0f + erff(t * 0.70710678118654752f));
    float f01 = g * w2a, f11 = g * w2b;

    #pragma unroll
    for (int m = 1; m < 32; m <<= 1) {
        f00 += __shfl_xor(f00, m, 32);
        f10 += __shfl_xor(f10, m, 32);
        f01 += __shfl_xor(f01, m, 32);
        f11 += __shfl_xor(f11, m, 32);
    }
    if (j == 0) {
        T4[entry] = make_float4(f00 + b2b[l*2+0], f10 + b2b[l*2+1],
                                f01 + b2b[l*2+0], f11 + b2b[l*2+1]);
    }
}

// 8 lanes per batch element (lane = position); k/v exchanged via __shfl width 8.
// FF via table lookup in nd; final vocab row = nd_final*u + w.
__global__ __launch_bounds__(256, 8) void seqtx_main(
    const int*   __restrict__ x,
    const float* __restrict__ Wqkv, const float* __restrict__ bqkv,
    const float* __restrict__ Wo,   const float* __restrict__ bo,
    const float* __restrict__ g1,   const float* __restrict__ be1,
    const float* __restrict__ g2,   const float* __restrict__ be2,
    const float* __restrict__ Wout, const float* __restrict__ bout,
    const float4* __restrict__ T4,
    float* __restrict__ out)
{
    __shared__ float snd[32];

    const int tid = threadIdx.x;
    const int sub = tid & 7;
    const int gid = blockIdx.x * 256 + tid;

    float h0 = (float)x[gid] * (1.0f / 255.0f);
    float h1 = (float)sub * (1.0f / 7.0f);
    float ndl = 0.0f;

    #pragma unroll
    for (int l = 0; l < NL; ++l) {
        // ---- QKV projection (uniform scalar weights) ----
        const float* wq = Wqkv + l * 12;
        const float* bq = bqkv + l * 6;
        float q0 = fmaf(wq[0],  h0, fmaf(wq[1],  h1, bq[0]));
        float q1 = fmaf(wq[2],  h0, fmaf(wq[3],  h1, bq[1]));
        float k0 = fmaf(wq[4],  h0, fmaf(wq[5],  h1, bq[2]));
        float k1 = fmaf(wq[6],  h0, fmaf(wq[7],  h1, bq[3]));
        float v0 = fmaf(wq[8],  h0, fmaf(wq[9],  h1, bq[4]));
        float v1 = fmaf(wq[10], h0, fmaf(wq[11], h1, bq[5]));

        // ---- attention, hd=1, scale=1; softmax without max-sub (|s| small) ----
        float q0e = q0 * 1.44269504f;    // fold log2(e) into q
        float q1e = q1 * 1.44269504f;
        float s0 = 0.0f, a0 = 0.0f, s1 = 0.0f, a1 = 0.0f;
        #pragma unroll
        for (int j = 0; j < SEQ; ++j) {
            float kj0 = __shfl(k0, j, SEQ);
            float vj0 = __shfl(v0, j, SEQ);
            float e0  = __builtin_amdgcn_exp2f(q0e * kj0);
            s0 += e0;  a0 = fmaf(e0, vj0, a0);
            float kj1 = __shfl(k1, j, SEQ);
            float vj1 = __shfl(v1, j, SEQ);
            float e1  = __builtin_amdgcn_exp2f(q1e * kj1);
            s1 += e1;  a1 = fmaf(e1, vj1, a1);
        }
        float o0 = a0 * __builtin_amdgcn_rcpf(s0);
        float o1 = a1 * __builtin_amdgcn_rcpf(s1);

        // ---- output proj + residual + LN1 (closed form, D=2) ----
        const float* wo = Wo + l * 4;
        float p0 = fmaf(wo[0], o0, fmaf(wo[1], o1, bo[l * 2 + 0]));
        float p1 = fmaf(wo[2], o0, fmaf(wo[3], o1, bo[l * 2 + 1]));
        float a = h0 + p0, c = h1 + p1;
        float d = 0.5f * (a - c);
        float nd = d * __builtin_amdgcn_rsqf(fmaf(d, d, 1e-5f));
        h0 = fmaf( nd, g1[l * 2 + 0], be1[l * 2 + 0]);
        h1 = fmaf(-nd, g1[l * 2 + 1], be1[l * 2 + 1]);

        // ---- FF via table lookup + lerp ----
        float tf = fmaf(nd, (float)(TBL_N / 2), (float)(TBL_N / 2)); // (nd+1)*N/2
        int   i  = (int)tf;
        i = (i < 0) ? 0 : ((i > TBL_N - 1) ? TBL_N - 1 : i);
        float fr = tf - (float)i;
        float4 e4 = T4[l * TBL_N + i];       // (f0_i, f1_i, f0_i1, f1_i1)
        float f0 = fmaf(fr, e4.z - e4.x, e4.x);
        float f1 = fmaf(fr, e4.w - e4.y, e4.y);

        // ---- residual + LN2 (exact) ----
        a = h0 + f0;  c = h1 + f1;
        d = 0.5f * (a - c);
        float nd2 = d * __builtin_amdgcn_rsqf(fmaf(d, d, 1e-5f));
        h0 = fmaf( nd2, g2[l * 2 + 0], be2[l * 2 + 0]);
        h1 = fmaf(-nd2, g2[l * 2 + 1], be2[l * 2 + 1]);
        ndl = nd2;
    }

    if (sub == SEQ - 1) snd[tid >> 3] = ndl;
    __syncthreads();

    // ---- vocab projection: out[row][v] = nd_final*u[v] + w[v], float4 stores ----
    const int r  = tid >> 6;              // wave id -> row offset (uniform/wave)
    const int cg = (tid & 63) * 4;

    const float2* wvp = reinterpret_cast<const float2*>(Wout);
    float2 wv0 = wvp[cg + 0];
    float2 wv1 = wvp[cg + 1];
    float2 wv2 = wvp[cg + 2];
    float2 wv3 = wvp[cg + 3];
    float4 bv  = *reinterpret_cast<const float4*>(bout + cg);
    float gf0 = g2[2], gf1 = g2[3], bf0 = be2[2], bf1 = be2[3];

    float u0 = wv0.x * gf0 - wv0.y * gf1,  w0 = fmaf(wv0.x, bf0, fmaf(wv0.y, bf1, bv.x));
    float u1 = wv1.x * gf0 - wv1.y * gf1,  w1 = fmaf(wv1.x, bf0, fmaf(wv1.y, bf1, bv.y));
    float u2 = wv2.x * gf0 - wv2.y * gf1,  w2 = fmaf(wv2.x, bf0, fmaf(wv2.y, bf1, bv.z));
    float u3 = wv3.x * gf0 - wv3.y * gf1,  w3 = fmaf(wv3.x, bf0, fmaf(wv3.y, bf1, bv.w));

    const size_t rowbase = (size_t)blockIdx.x * 32;
    #pragma unroll
    for (int it = 0; it < 8; ++it) {
        int row = it * 4 + r;
        float ndv = snd[row];             // LDS broadcast (wave-uniform row)
        float4 res;
        res.x = fmaf(ndv, u0, w0);
        res.y = fmaf(ndv, u1, w1);
        res.z = fmaf(ndv, u2, w2);
        res.w = fmaf(ndv, u3, w3);
        *reinterpret_cast<float4*>(&out[(rowbase + row) * VOCAB + cg]) = res;
    }
}

extern "C" void kernel_launch(void* const* d_in, const int* in_sizes, int n_in,
                              void* d_out, int out_size, void* d_ws, size_t ws_size,
                              hipStream_t stream) {
    const int*   x    = (const int*)  d_in[0];
    const float* Wqkv = (const float*)d_in[1];
    const float* bqkv = (const float*)d_in[2];
    const float* Wo   = (const float*)d_in[3];
    const float* bo   = (const float*)d_in[4];
    const float* W1   = (const float*)d_in[5];
    const float* b1   = (const float*)d_in[6];
    const float* W2   = (const float*)d_in[7];
    const float* b2   = (const float*)d_in[8];
    const float* g1   = (const float*)d_in[9];
    const float* be1  = (const float*)d_in[10];
    const float* g2   = (const float*)d_in[11];
    const float* be2  = (const float*)d_in[12];
    const float* Wout = (const float*)d_in[13];
    const float* bout = (const float*)d_in[14];
    float* out = (float*)d_out;

    float4* T4 = (float4*)d_ws;   // 2*4096*16B = 128 KiB

    // NL*TBL_N entries, 32 threads each -> 262144 threads -> 1024 blocks
    build_tables_par<<<(NL * TBL_N * 32) / 256, 256, 0, stream>>>(
        W1, b1, W2, b2, g1, be1, b2, T4);

    seqtx_main<<<BATCH / 32, 256, 0, stream>>>(
        x, Wqkv, bqkv, Wo, bo, g1, be1, g2, be2, Wout, bout, T4, out);
}